// Round 10
// baseline (727.964 us; speedup 1.0000x reference)
//
#include <hip/hip_runtime.h>

#define TT 2048
#define HH 32
#define BB 512
#define SCL 2.8853900817779268f   // 2*log2(e): tanh(x) = 1 - 2/(2^(SCL*x)+1)

typedef float f32x2 __attribute__((ext_vector_type(2)));

#define PKFMA(acc, a, b) asm("v_pk_fma_f32 %0, %1, %2, %0" : "+v"(acc) : "v"(a), "v"(b))

__device__ __forceinline__ float tanh2(float s) {
    // s pre-scaled by SCL: tanh = 1 - 2/(exp2(s)+1)
    float e;
    asm("v_exp_f32 %0, %1" : "=v"(e) : "v"(s));
    float r = __builtin_amdgcn_rcpf(e + 1.0f);
    return fmaf(-2.0f, r, 1.0f);
}

__global__ __launch_bounds__(64, 1) void rnn_fused(
    const float* __restrict__ x,      // [B, T, 1]
    const float* __restrict__ hid,    // [2, B, H]
    const float* __restrict__ W_ih0,  // [H, 1]
    const float* __restrict__ W_hh0,  // [H, H]
    const float* __restrict__ b_ih0,  // [H]
    const float* __restrict__ b_hh0,  // [H]
    const float* __restrict__ W_ih1,  // [H, H]
    const float* __restrict__ W_hh1,  // [H, H]
    const float* __restrict__ b_ih1,  // [H]
    const float* __restrict__ b_hh1,  // [H]
    const float* __restrict__ W_fc,   // [1, H]
    const float* __restrict__ b_fc,   // [1]
    float* __restrict__ out)          // [B*T] outs ++ [2*B*H] hidden
{
    const int lane   = (int)threadIdx.x;   // 0..63
    const int i      = lane & 31;          // unit index within the half
    const bool lower = lane < 32;          // lower: layer0 + fc; upper: layer1
    const int bA     = (int)blockIdx.x * 2;
    const int bB     = bA + 1;

    __shared__ __align__(16) float shA[64], shB[64];  // [0..31]=h0, [32..63]=h1
    __shared__ float xsA[32], xsB[32];                // 32-step x windows

    // ---- per-lane weights (shared by both chains) ----
    const float* rowA = lower ? (W_hh0 + i * HH) : (W_ih1 + i * HH);
    const float* rowB = lower ? W_fc             : (W_hh1 + i * HH);
    const float  sclB = lower ? 1.0f : SCL;      // fc weights stay unscaled
    f32x2 wA[16], wB[16];
#pragma unroll
    for (int j = 0; j < 16; ++j) {
        wA[j] = f32x2{SCL * rowA[2 * j], SCL * rowA[2 * j + 1]};
        wB[j] = f32x2{sclB * rowB[2 * j], sclB * rowB[2 * j + 1]};
    }
    const float wx   = lower ? (SCL * W_ih0[i]) : 0.0f;
    const float bias = SCL * (lower ? (b_ih0[i] + b_hh0[i])
                                    : (b_ih1[i] + b_hh1[i]));
    const float sel  = lower ? 0.0f : 1.0f;
    const float bfc  = b_fc[0];

    // ---- initial hidden into LDS ----
    const float h_initA = lower ? hid[bA * HH + i] : hid[BB * HH + bA * HH + i];
    const float h_initB = lower ? hid[bB * HH + i] : hid[BB * HH + bB * HH + i];
    shA[lane] = h_initA;
    shB[lane] = h_initB;

    const float* xrowA = x + bA * TT;
    const float* xrowB = x + bB * TT;
    float* orowA = out + bA * TT;
    float* orowB = out + bB * TT;

    xsA[i] = xrowA[i];
    xsB[i] = xrowB[i];
    float xnxtA = xrowA[32 + i];
    float xnxtB = xrowB[32 + i];

    float hnA = h_initA, hnB = h_initB;

    // persistent register images: q[0..7] = h0-half, q[8..15] = h1-half
    float4 qA[16], qB[16];
#pragma unroll
    for (int m = 0; m < 16; ++m) qA[m] = *(const float4*)&shA[4 * m];
#pragma unroll
    for (int m = 0; m < 16; ++m) qB[m] = *(const float4*)&shB[4 * m];

    // R7's proven STEP, instantiated per-chain with DIRECT names (no pointer
    // params -> full SROA; launch_bounds(64,1) -> no spill).
#define MAKE_STEP(NAME, q, hn, shp, xsp, orowp)                             \
    auto NAME = [&](int k, bool do_store, int off) {                        \
        float xv = xsp[k];                                                  \
        f32x2 A0 = {bias, 0.f}, A1 = {0.f, 0.f};                            \
        f32x2 B0 = {0.f, 0.f},  B1 = {0.f, 0.f};                            \
        _Pragma("unroll")                                                   \
        for (int m = 0; m < 8; ++m) {                                       \
            f32x2 qa = {q[m].x, q[m].y}, qb = {q[m].z, q[m].w};             \
            PKFMA(A0, wA[2 * m], qa);                                       \
            PKFMA(A1, wA[2 * m + 1], qb);                                   \
        }                                                                   \
        _Pragma("unroll")                                                   \
        for (int m = 0; m < 8; ++m) {                                       \
            f32x2 qa = {q[8 + m].x, q[8 + m].y};                            \
            f32x2 qb = {q[8 + m].z, q[8 + m].w};                            \
            PKFMA(B0, wB[2 * m], qa);                                       \
            PKFMA(B1, wB[2 * m + 1], qb);                                   \
        }                                                                   \
        f32x2 As = A0 + A1, Bs = B0 + B1;                                   \
        float s1 = As.x + As.y;                                             \
        float s2 = Bs.x + Bs.y;                                             \
        float pre = fmaf(sel, s2, fmaf(wx, xv, s1));                        \
        float h = tanh2(pre);                                               \
        shp[lane] = h;                                                      \
        hn = h;                                                             \
        if (do_store && lane == 0) orowp[off] = s2 + bfc;                   \
        _Pragma("unroll")                                                   \
        for (int m = 0; m < 16; ++m) q[m] = *(const float4*)&shp[4 * m];    \
    }

#define MAKE_PEEL(NAME, q, hn, shp, xsp, h_init_)                           \
    auto NAME = [&]() {                                                     \
        float xv = xsp[0];                                                  \
        f32x2 A0 = {bias, 0.f}, A1 = {0.f, 0.f};                            \
        _Pragma("unroll")                                                   \
        for (int m = 0; m < 8; ++m) {                                       \
            f32x2 qa = {q[m].x, q[m].y}, qb = {q[m].z, q[m].w};             \
            PKFMA(A0, wA[2 * m], qa);                                       \
            PKFMA(A1, wA[2 * m + 1], qb);                                   \
        }                                                                   \
        f32x2 As = A0 + A1;                                                 \
        float h0c = tanh2(fmaf(wx, xv, As.x + As.y));                       \
        float ew = lower ? h0c : h_init_;                                   \
        shp[lane] = ew;                                                     \
        hn = ew;                                                            \
        _Pragma("unroll")                                                   \
        for (int m = 0; m < 16; ++m) q[m] = *(const float4*)&shp[4 * m];    \
    }

#define MAKE_FINFC(NAME, q, orowp)                                          \
    auto NAME = [&]() {                                                     \
        f32x2 B0 = {0.f, 0.f}, B1 = {0.f, 0.f};                             \
        _Pragma("unroll")                                                   \
        for (int m = 0; m < 8; ++m) {                                       \
            f32x2 qa = {q[8 + m].x, q[8 + m].y};                            \
            f32x2 qb = {q[8 + m].z, q[8 + m].w};                            \
            PKFMA(B0, wB[2 * m], qa);                                       \
            PKFMA(B1, wB[2 * m + 1], qb);                                   \
        }                                                                   \
        f32x2 Bs = B0 + B1;                                                 \
        if (lane == 0) orowp[TT - 1] = (Bs.x + Bs.y) + bfc;                 \
    }

    MAKE_STEP(STEPA, qA, hnA, shA, xsA, orowA);
    MAKE_STEP(STEPB, qB, hnB, shB, xsB, orowB);
    MAKE_PEEL(PEELA, qA, hnA, shA, xsA, h_initA);
    MAKE_PEEL(PEELB, qB, hnB, shB, xsB, h_initB);
    MAKE_FINFC(FINA, qA, orowA);
    MAKE_FINFC(FINB, qB, orowB);

    // ===== tau = 0 peel =====
    PEELA();
    PEELB();

    // ===== block 0: tau = 1..31 (stores begin at tau = 2) =====
#pragma unroll 8
    for (int k = 1; k < 32; ++k) {
        STEPA(k, k >= 2, k - 2);
        STEPB(k, k >= 2, k - 2);
    }
    xsA[i] = xnxtA;  xnxtA = xrowA[64 + i];
    xsB[i] = xnxtB;  xnxtB = xrowB[64 + i];

    // ===== main: tau = 32..2047 =====
    for (int tb = 1; tb < 64; ++tb) {
        const int base = tb * 32;
#pragma unroll 8
        for (int k = 0; k < 32; ++k) {
            STEPA(k, true, base + k - 2);
            STEPB(k, true, base + k - 2);
        }
        int nidx = (tb + 2) * 32 + i;
        if (nidx >= TT) nidx = TT - 1;
        xsA[i] = xnxtA;  xnxtA = xrowA[nidx];
        xsB[i] = xnxtB;  xnxtB = xrowB[nidx];
    }

    const float h0_finA = hnA;    // lower lanes: h0[2047]
    const float h0_finB = hnB;

    // ===== epilogue tau = 2048: h1[2047] + out[2046] =====
    STEPA(0, true, TT - 2);
    STEPB(0, true, TT - 2);

    // ===== epilogue tau = 2049: out[2047] = wfc . h1[2047] + bfc =====
    FINA();
    FINB();

    // ===== final hidden [2, B, H] =====
    if (lower) {
        out[BB * TT + bA * HH + i] = h0_finA;
        out[BB * TT + bB * HH + i] = h0_finB;
    } else {
        out[BB * TT + BB * HH + bA * HH + i] = hnA;   // h1[2047]
        out[BB * TT + BB * HH + bB * HH + i] = hnB;
    }
}

extern "C" void kernel_launch(void* const* d_in, const int* in_sizes, int n_in,
                              void* d_out, int out_size, void* d_ws, size_t ws_size,
                              hipStream_t stream) {
    const float* xp    = (const float*)d_in[0];
    const float* hid   = (const float*)d_in[1];
    const float* Wih0  = (const float*)d_in[2];
    const float* Whh0  = (const float*)d_in[3];
    const float* bih0  = (const float*)d_in[4];
    const float* bhh0  = (const float*)d_in[5];
    const float* Wih1  = (const float*)d_in[6];
    const float* Whh1  = (const float*)d_in[7];
    const float* bih1  = (const float*)d_in[8];
    const float* bhh1  = (const float*)d_in[9];
    const float* Wfc   = (const float*)d_in[10];
    const float* bfc   = (const float*)d_in[11];
    float* outp        = (float*)d_out;

    rnn_fused<<<BB / 2, 64, 0, stream>>>(xp, hid, Wih0, Whh0, bih0, bhh0,
                                         Wih1, Whh1, bih1, bhh1, Wfc, bfc, outp);
}

// Round 11
// 327.692 us; speedup vs baseline: 2.2215x; 2.2215x over previous
//
#include <hip/hip_runtime.h>

#define TT 2048
#define HH 32
#define BB 512
#define SCL 2.8853900817779268f   // 2*log2(e): tanh(x) = 1 - 2/(2^(SCL*x)+1)

typedef float f32x2 __attribute__((ext_vector_type(2)));

#define PKFMA(acc, a, b) asm("v_pk_fma_f32 %0, %1, %2, %0" : "+v"(acc) : "v"(a), "v"(b))

__device__ __forceinline__ float tanh2(float s) {
    // s pre-scaled by SCL: tanh = 1 - 2/(exp2(s)+1)
    float e;
    asm("v_exp_f32 %0, %1" : "=v"(e) : "v"(s));
    float r = __builtin_amdgcn_rcpf(e + 1.0f);
    return fmaf(-2.0f, r, 1.0f);
}

__global__ __launch_bounds__(64, 1) void rnn_fused(
    const float* __restrict__ x,      // [B, T, 1]
    const float* __restrict__ hid,    // [2, B, H]
    const float* __restrict__ W_ih0,  // [H, 1]
    const float* __restrict__ W_hh0,  // [H, H]
    const float* __restrict__ b_ih0,  // [H]
    const float* __restrict__ b_hh0,  // [H]
    const float* __restrict__ W_ih1,  // [H, H]
    const float* __restrict__ W_hh1,  // [H, H]
    const float* __restrict__ b_ih1,  // [H]
    const float* __restrict__ b_hh1,  // [H]
    const float* __restrict__ W_fc,   // [1, H]
    const float* __restrict__ b_fc,   // [1]
    float* __restrict__ out)          // [B*T] outs ++ [2*B*H] hidden
{
    const int lane   = (int)threadIdx.x;   // 0..63
    const int i      = lane & 31;          // unit index within the half
    const bool lower = lane < 32;          // lower: layer0; upper: layer1
    const int b      = (int)blockIdx.x;    // one batch per wave

    __shared__ __align__(16) float sh[64];       // [0..31]=h0, [32..63]=h1
    __shared__ float xs[32];                     // current 32-step x window
    __shared__ __align__(16) float ring[32][68]; // h1 history rows (cols 32..63)

    // ---- per-lane weights ----
    const float* rowA = lower ? (W_hh0 + i * HH) : (W_ih1 + i * HH);
    const float* rowB = W_hh1 + i * HH + (lower ? 0 : 16);  // half-K split
    const float* wfp  = W_fc + (lower ? 0 : 16);            // fc half-K split
    f32x2 wA[16], wB[8], wf[8];
#pragma unroll
    for (int j = 0; j < 16; ++j)
        wA[j] = f32x2{SCL * rowA[2 * j], SCL * rowA[2 * j + 1]};
#pragma unroll
    for (int j = 0; j < 8; ++j) {
        wB[j] = f32x2{SCL * rowB[2 * j], SCL * rowB[2 * j + 1]};
        wf[j] = f32x2{wfp[2 * j], wfp[2 * j + 1]};   // unscaled
    }
    const float wx   = lower ? (SCL * W_ih0[i]) : 0.0f;
    const float bias = SCL * (lower ? (b_ih0[i] + b_hh0[i])
                                    : (b_ih1[i] + b_hh1[i]));
    const float sel  = lower ? 0.0f : 1.0f;
    const float bfc  = b_fc[0];
    const int   hb   = 32 + (lower ? 0 : 16);    // h1 half-image base in sh/ring

    // ---- initial hidden into LDS ----
    const float h_init = lower ? hid[b * HH + i] : hid[BB * HH + b * HH + i];
    sh[lane] = h_init;

    const float* xrow = x + b * TT;
    float* orow = out + b * TT;

    xs[i] = xrow[i];
    float xnxt = xrow[32 + i];

    float hn = h_init;           // lower: current h0; upper: current h1

    // register images: q = full h0 (32), bq = this half's h1 slice (16)
    float4 q[8], bq[4];
#pragma unroll
    for (int m = 0; m < 8; ++m) q[m]  = *(const float4*)&sh[4 * m];
#pragma unroll
    for (int m = 0; m < 4; ++m) bq[m] = *(const float4*)&sh[hb + 4 * m];

    // Step tau: q=h0[tau-1], bq=h1[tau-2] half. Computes h0[tau] (lower) /
    // h1[tau-1] (upper), writes sh + ring[slot], reloads images.
    auto STEP = [&](int k, int slot) {
        // B-phase first: its shfl latency hides under the A-dot
        f32x2 B0 = {0.f, 0.f}, B1 = {0.f, 0.f};
#pragma unroll
        for (int m = 0; m < 4; ++m) {
            f32x2 ba = {bq[m].x, bq[m].y}, bb = {bq[m].z, bq[m].w};
            PKFMA(B0, wB[2 * m], ba);
            PKFMA(B1, wB[2 * m + 1], bb);
        }
        f32x2 Bs = B0 + B1;
        float s2p = Bs.x + Bs.y;
        float s2o = __shfl_xor(s2p, 32);
        float xv = xs[k];
        f32x2 A0 = {bias, 0.f}, A1 = {0.f, 0.f};
#pragma unroll
        for (int m = 0; m < 8; ++m) {
            f32x2 qa = {q[m].x, q[m].y}, qb = {q[m].z, q[m].w};
            PKFMA(A0, wA[2 * m], qa);
            PKFMA(A1, wA[2 * m + 1], qb);
        }
        f32x2 As = A0 + A1;
        float s1 = As.x + As.y;
        float s2 = s2p + s2o;                    // full Whh1[i].h1 (both halves)
        float pre = fmaf(sel, s2, fmaf(wx, xv, s1));
        float h = tanh2(pre);
        sh[lane] = h;
        ring[slot][lane] = h;                    // cols 32..63 = h1 history
        hn = h;
#pragma unroll
        for (int m = 0; m < 4; ++m) bq[m] = *(const float4*)&sh[hb + 4 * m];
#pragma unroll
        for (int m = 0; m < 8; ++m) q[m]  = *(const float4*)&sh[4 * m];
    };

    // Flush: out[.] = wfc . h1 for 32 ring rows; lane s handles row s, K-half
    // per wave-half, combined by shfl. basep = base' (see slot math).
    auto FLUSH = [&](int basep, bool first) {
        f32x2 F0 = {0.f, 0.f}, F1 = {0.f, 0.f};
#pragma unroll
        for (int m = 0; m < 4; ++m) {
            float4 r = *(const float4*)&ring[i][hb + 4 * m];
            f32x2 ra = {r.x, r.y}, rb = {r.z, r.w};
            PKFMA(F0, wf[2 * m], ra);
            PKFMA(F1, wf[2 * m + 1], rb);
        }
        f32x2 Fs = F0 + F1;
        float fp = Fs.x + Fs.y;
        float ff = fp + __shfl_xor(fp, 32) + bfc;
        int o = (i == 31) ? basep - 1 : basep + i;   // slot31 holds h1[basep-1]
        if (lower && !(first && i == 31)) orow[o] = ff;
    };

    // ===== tau = 0 peel: A-only; upper preserves h1[-1]; no ring =====
    {
        float xv = xs[0];
        f32x2 A0 = {bias, 0.f}, A1 = {0.f, 0.f};
#pragma unroll
        for (int m = 0; m < 8; ++m) {
            f32x2 qa = {q[m].x, q[m].y}, qb = {q[m].z, q[m].w};
            PKFMA(A0, wA[2 * m], qa);
            PKFMA(A1, wA[2 * m + 1], qb);
        }
        f32x2 As = A0 + A1;
        float h0c = tanh2(fmaf(wx, xv, As.x + As.y));
        float ew = lower ? h0c : h_init;
        sh[lane] = ew;
        hn = ew;
#pragma unroll
        for (int m = 0; m < 4; ++m) bq[m] = *(const float4*)&sh[hb + 4 * m];
#pragma unroll
        for (int m = 0; m < 8; ++m) q[m]  = *(const float4*)&sh[4 * m];
    }

    // ===== block 0: tau = 1..31 -> ring slots 0..30 =====
#pragma unroll
    for (int k = 1; k < 32; ++k) {
        STEP(k, k - 1);
    }
    xs[i] = xnxt;
    xnxt = xrow[64 + i];

    // ===== main: tb = 1..63, tau = 32tb + k =====
    for (int tb = 1; tb < 64; ++tb) {
        FLUSH(32 * (tb - 1), tb == 1);     // out[32(tb-1)-1 .. 32(tb-1)+30]
#pragma unroll
        for (int k = 0; k < 32; ++k) {
            STEP(k, (k + 31) & 31);        // slot (tau-1) & 31
        }
        xs[i] = xnxt;
        int nidx = 32 * (tb + 2) + i;
        if (nidx >= TT) nidx = TT - 1;
        xnxt = xrow[nidx];
    }

    const float h0_fin = hn;               // lower: h0[2047]

    // ===== epilogue tau = 2048: h1[2047] only (no writes) =====
    {
        f32x2 B0 = {0.f, 0.f}, B1 = {0.f, 0.f};
#pragma unroll
        for (int m = 0; m < 4; ++m) {
            f32x2 ba = {bq[m].x, bq[m].y}, bb = {bq[m].z, bq[m].w};
            PKFMA(B0, wB[2 * m], ba);
            PKFMA(B1, wB[2 * m + 1], bb);
        }
        f32x2 Bs = B0 + B1;
        float s2p = Bs.x + Bs.y;
        float s2 = s2p + __shfl_xor(s2p, 32);
        f32x2 A0 = {bias, 0.f}, A1 = {0.f, 0.f};
#pragma unroll
        for (int m = 0; m < 8; ++m) {
            f32x2 qa = {q[m].x, q[m].y}, qb = {q[m].z, q[m].w};
            PKFMA(A0, wA[2 * m], qa);
            PKFMA(A1, wA[2 * m + 1], qb);
        }
        f32x2 As = A0 + A1;
        float s1 = As.x + As.y;
        float h = tanh2(fmaf(sel, s2, s1));
        if (!lower) hn = h;                // h1[2047]
    }

    // ===== final flush: ring rows cover h1[2015..2046] -> out[2015..2046] =====
    FLUSH(2016, false);

    // ===== out[2047] = wfc . h1[2047] via butterfly over upper hn =====
    {
        float v = lower ? 0.0f : (W_fc[i] * hn);
        v += __shfl_xor(v, 1);
        v += __shfl_xor(v, 2);
        v += __shfl_xor(v, 4);
        v += __shfl_xor(v, 8);
        v += __shfl_xor(v, 16);
        v += __shfl_xor(v, 32);
        if (lane == 0) orow[TT - 1] = v + bfc;
    }

    // ===== final hidden [2, B, H] =====
    if (lower) {
        out[BB * TT + b * HH + i] = h0_fin;            // h0[2047]
    } else {
        out[BB * TT + BB * HH + b * HH + i] = hn;      // h1[2047]
    }
}

extern "C" void kernel_launch(void* const* d_in, const int* in_sizes, int n_in,
                              void* d_out, int out_size, void* d_ws, size_t ws_size,
                              hipStream_t stream) {
    const float* xp    = (const float*)d_in[0];
    const float* hid   = (const float*)d_in[1];
    const float* Wih0  = (const float*)d_in[2];
    const float* Whh0  = (const float*)d_in[3];
    const float* bih0  = (const float*)d_in[4];
    const float* bhh0  = (const float*)d_in[5];
    const float* Wih1  = (const float*)d_in[6];
    const float* Whh1  = (const float*)d_in[7];
    const float* bih1  = (const float*)d_in[8];
    const float* bhh1  = (const float*)d_in[9];
    const float* Wfc   = (const float*)d_in[10];
    const float* bfc   = (const float*)d_in[11];
    float* outp        = (float*)d_out;

    rnn_fused<<<BB, 64, 0, stream>>>(xp, hid, Wih0, Whh0, bih0, bhh0,
                                     Wih1, Whh1, bih1, bhh1, Wfc, bfc, outp);
}